// Round 2
// baseline (824.447 us; speedup 1.0000x reference)
//
#include <hip/hip_runtime.h>
#include <math.h>

// LCGLoss: B=256, L=512, D=512.
// S[(b,l),k] = (text @ C)[(b,l),k],  C = W_ML^T @ image_proj^T / tau  (D x B)
// loss = mean over valid (i,l) of 0.5*(denom_log + logaddexp(s_iji, cross_log[i])) - s_iji

#define B_ 256
#define L_ 512
#define D_ 512
#define ROWS (B_ * L_)      // 131072
#define NT (ROWS / 64)      // 2048 row-tiles
#define NEG_INF (-INFINITY)

// ---------------- K0: image_proj[k][e] = sum_d image[k][d] * W_MV[e][d] ----------------
__global__ __launch_bounds__(256) void ip_kernel(const float* __restrict__ img,
                                                 const float* __restrict__ Wmv,
                                                 float* __restrict__ ip) {
    int k = blockIdx.x;
    __shared__ float s[D_];
    for (int d = threadIdx.x; d < D_; d += 256) s[d] = img[k * D_ + d];
    __syncthreads();
    for (int e = threadIdx.x; e < D_; e += 256) {
        const float* w = Wmv + (size_t)e * D_;
        float acc = 0.f;
        for (int d = 0; d < D_; d += 4) {
            float4 wv = *(const float4*)(w + d);
            acc += wv.x * s[d] + wv.y * s[d + 1] + wv.z * s[d + 2] + wv.w * s[d + 3];
        }
        ip[k * D_ + e] = acc;
    }
}

// ---------------- K1: Cm[d][k] = sum_e W_ML[e][d] * ip[k][e] * (1/tau_c) ----------------
__global__ __launch_bounds__(256) void c_kernel(const float* __restrict__ Wml,
                                                const float* __restrict__ ip,
                                                const float* __restrict__ tau,
                                                float* __restrict__ Cm) {
    int k = blockIdx.x;
    __shared__ float s[D_];
    for (int e = threadIdx.x; e < D_; e += 256) s[e] = ip[k * D_ + e];
    __syncthreads();
    float inv_tau = 1.0f / fmaxf(tau[0], 0.001f);
    for (int d = threadIdx.x; d < D_; d += 256) {
        float acc = 0.f;
        for (int e = 0; e < D_; e++) acc += Wml[(size_t)e * D_ + d] * s[e];
        Cm[d * B_ + k] = acc * inv_tau;
    }
}

// ---------------- Kmask: mbits[l*4+w] bit j = valid[w*64+j, l] ----------------
__global__ __launch_bounds__(256) void mask_kernel(const int* __restrict__ pad,
                                                   unsigned long long* __restrict__ mbits) {
    int l = blockIdx.x;
    int w = threadIdx.x >> 6;
    int j = threadIdx.x & 63;
    unsigned long long bal = __ballot(pad[(w * 64 + j) * L_ + l] == 0);
    if (j == 0) mbits[l * 4 + w] = bal;
}

// ---------------- K2: GEMM (64 rows x 256 cols per block) + fused reductions ----------------
// thread (cx = tid&31, ry = tid>>5): rows ry*8+i, cols cx*8+j
__global__ __launch_bounds__(256) void gemm_reduce_kernel(
    const float* __restrict__ text, const float* __restrict__ Cm,
    const unsigned long long* __restrict__ mbits,
    float* __restrict__ denom, float* __restrict__ siji,
    float* __restrict__ crossM, float* __restrict__ crossS) {
    // LDS: staging a_s[16][64] (transposed) + b_s[16][256]  |  epilogue Sh[32][257] + pm/ps[128] + rv[32]
    __shared__ __align__(16) float lds[8512];
    float* a_s = lds;             // 1024 floats
    float* b_s = lds + 1024;      // 4096 floats
    float* Sh  = lds;             // 32*257 = 8224 floats
    float* pm  = lds + 8224;      // 128
    float* ps  = lds + 8352;      // 128
    float* rvf = lds + 8480;      // 32

    const int tile = blockIdx.x;
    const int row0 = tile * 64;
    const int bIdx = row0 >> 9;       // batch index (same for all 64 rows: 64 | 512)
    const int l0 = row0 & 511;
    const int tid = threadIdx.x;
    const int cx = tid & 31;
    const int ry = tid >> 5;

    float acc[8][8];
#pragma unroll
    for (int i = 0; i < 8; i++)
#pragma unroll
        for (int j = 0; j < 8; j++) acc[i][j] = 0.f;

    const int ar = tid >> 2;          // text row 0..63
    const int ak = (tid & 3) * 4;     // k sub-offset 0,4,8,12
    const int bkk = tid >> 4;         // C row 0..15
    const int bc = (tid & 15) * 4;    // C col base; cols bc + {0,64,128,192}
    const float* textRow = text + (size_t)(row0 + ar) * D_;

#pragma unroll 1
    for (int ks = 0; ks < D_; ks += 16) {
        float4 av  = *(const float4*)(textRow + ks + ak);
        const float* crow = Cm + (size_t)(ks + bkk) * B_ + bc;
        float4 bv0 = *(const float4*)(crow);
        float4 bv1 = *(const float4*)(crow + 64);
        float4 bv2 = *(const float4*)(crow + 128);
        float4 bv3 = *(const float4*)(crow + 192);
        __syncthreads();
        a_s[(ak + 0) * 64 + ar] = av.x;
        a_s[(ak + 1) * 64 + ar] = av.y;
        a_s[(ak + 2) * 64 + ar] = av.z;
        a_s[(ak + 3) * 64 + ar] = av.w;
        *(float4*)(b_s + bkk * 256 + bc)       = bv0;
        *(float4*)(b_s + bkk * 256 + bc + 64)  = bv1;
        *(float4*)(b_s + bkk * 256 + bc + 128) = bv2;
        *(float4*)(b_s + bkk * 256 + bc + 192) = bv3;
        __syncthreads();
#pragma unroll
        for (int kk = 0; kk < 16; kk++) {
            float4 a0 = *(const float4*)(a_s + kk * 64 + ry * 8);
            float4 a1 = *(const float4*)(a_s + kk * 64 + ry * 8 + 4);
            float4 b0 = *(const float4*)(b_s + kk * 256 + cx * 8);
            float4 b1 = *(const float4*)(b_s + kk * 256 + cx * 8 + 4);
            float a[8] = {a0.x, a0.y, a0.z, a0.w, a1.x, a1.y, a1.z, a1.w};
            float b[8] = {b0.x, b0.y, b0.z, b0.w, b1.x, b1.y, b1.z, b1.w};
#pragma unroll
            for (int i = 0; i < 8; i++)
#pragma unroll
                for (int j = 0; j < 8; j++) acc[i][j] = fmaf(a[i], b[j], acc[i][j]);
        }
    }

    // -------- epilogue: two 32-row halves through LDS --------
    float cm = NEG_INF, cs = 0.f;           // cross partial for column tid
    const int mw = bIdx >> 6, mb = bIdx & 63;

    for (int h = 0; h < 2; h++) {
        __syncthreads();                    // prev-half reads / GEMM reads done
        if ((ry >> 2) == h) {
            int rbase = (ry & 3) * 8;
#pragma unroll
            for (int i = 0; i < 8; i++)
#pragma unroll
                for (int j = 0; j < 8; j++)
                    Sh[(rbase + i) * 257 + cx * 8 + j] = acc[i][j];
        }
        if (tid < 32) {
            int l = l0 + h * 32 + tid;
            rvf[tid] = (float)((mbits[l * 4 + mw] >> mb) & 1ULL);  // valid[bIdx, l]
        }
        __syncthreads();

        // cross partial: column = tid, exclude column == bIdx; rows need valid[bIdx,l]
        if (tid != bIdx) {
            float m2 = NEG_INF;
            for (int r = 0; r < 32; r++)
                if (rvf[r] != 0.f) m2 = fmaxf(m2, Sh[r * 257 + tid]);
            if (m2 > NEG_INF) {
                float s2 = 0.f;
                for (int r = 0; r < 32; r++)
                    if (rvf[r] != 0.f) s2 += expf(Sh[r * 257 + tid] - m2);
                if (cm == NEG_INF) { cm = m2; cs = s2; }
                else {
                    float M = fmaxf(cm, m2);
                    cs = cs * expf(cm - M) + s2 * expf(m2 - M);
                    cm = M;
                }
            }
        }
        // denom partials: 128 threads, (row = tid&31, grp = tid>>5 covering 64 cols)
        if (tid < 128) {
            int row = tid & 31, grp = tid >> 5;
            int l = l0 + h * 32 + row;
            unsigned long long bits = mbits[l * 4 + grp];   // valid[k,l] for k in grp*64..+63
            const float* Srow = Sh + row * 257 + grp * 64;
            float m = NEG_INF;
            for (int c = 0; c < 64; c++)
                if ((bits >> c) & 1ULL) m = fmaxf(m, Srow[c]);
            float s = 0.f;
            if (m > NEG_INF)
                for (int c = 0; c < 64; c++)
                    if ((bits >> c) & 1ULL) s += expf(Srow[c] - m);
            pm[grp * 32 + row] = m;
            ps[grp * 32 + row] = s;
        }
        __syncthreads();
        if (tid < 32) {
            float m0 = pm[tid], m1 = pm[32 + tid], m2 = pm[64 + tid], m3 = pm[96 + tid];
            float M = fmaxf(fmaxf(m0, m1), fmaxf(m2, m3));
            float dl;
            if (M == NEG_INF) dl = NEG_INF;
            else {
                float s = ps[tid] * expf(m0 - M) + ps[32 + tid] * expf(m1 - M) +
                          ps[64 + tid] * expf(m2 - M) + ps[96 + tid] * expf(m3 - M);
                dl = M + logf(s);
            }
            int gr = row0 + h * 32 + tid;
            denom[gr] = dl;
            siji[gr] = Sh[tid * 257 + bIdx];
        }
    }
    // transposed layout [col][tile] so K3 reads coalesced
    crossM[(size_t)tid * NT + tile] = cm;
    crossS[(size_t)tid * NT + tile] = cs;
}

// ---------------- K3: cross_log[i] = merge of 2048 (m,s) partials ----------------
__global__ __launch_bounds__(256) void cross_combine_kernel(const float* __restrict__ crossM,
                                                            const float* __restrict__ crossS,
                                                            float* __restrict__ crossLog) {
    int i = blockIdx.x;
    int tid = threadIdx.x;
    float m = NEG_INF, s = 0.f;
    for (int e = 0; e < NT / 256; e++) {
        int t = e * 256 + tid;
        float m2 = crossM[(size_t)i * NT + t];
        float s2 = crossS[(size_t)i * NT + t];
        if (m2 > NEG_INF) {
            if (m == NEG_INF) { m = m2; s = s2; }
            else {
                float M = fmaxf(m, m2);
                s = s * expf(m - M) + s2 * expf(m2 - M);
                m = M;
            }
        }
    }
    __shared__ float sm[256], ss[256];
    sm[tid] = m; ss[tid] = s;
    __syncthreads();
    for (int off = 128; off > 0; off >>= 1) {
        if (tid < off) {
            float m1 = sm[tid], s1 = ss[tid];
            float m2 = sm[tid + off], s2 = ss[tid + off];
            float M = fmaxf(m1, m2);
            float sv;
            if (M == NEG_INF) sv = 0.f;
            else sv = s1 * expf(m1 - M) + s2 * expf(m2 - M);
            sm[tid] = M; ss[tid] = sv;
        }
        __syncthreads();
    }
    if (tid == 0) crossLog[i] = (sm[0] == NEG_INF) ? NEG_INF : sm[0] + logf(ss[0]);
}

// ---------------- K4: per-block partial loss sums ----------------
__global__ __launch_bounds__(256) void loss_partial_kernel(
    const int* __restrict__ pad, const float* __restrict__ denom,
    const float* __restrict__ siji, const float* __restrict__ crossLog,
    float* __restrict__ psum, float* __restrict__ pcnt) {
    int tid = threadIdx.x;
    int idx = blockIdx.x * 256 + tid;
    float term = 0.f, cnt = 0.f;
    if (pad[idx] == 0) {
        float dl = denom[idx], sv = siji[idx], cl = crossLog[idx >> 9];
        float M = fmaxf(sv, cl);
        float neg = M + log1pf(expf(-fabsf(sv - cl)));   // logaddexp
        term = 0.5f * (dl + neg) - sv;
        cnt = 1.f;
    }
    __shared__ float bs[256], bc[256];
    bs[tid] = term; bc[tid] = cnt;
    __syncthreads();
    for (int off = 128; off > 0; off >>= 1) {
        if (tid < off) { bs[tid] += bs[tid + off]; bc[tid] += bc[tid + off]; }
        __syncthreads();
    }
    if (tid == 0) { psum[blockIdx.x] = bs[0]; pcnt[blockIdx.x] = bc[0]; }
}

// ---------------- K5: final reduce of 512 partials ----------------
__global__ __launch_bounds__(256) void final_kernel(const float* __restrict__ psum,
                                                    const float* __restrict__ pcnt,
                                                    float* __restrict__ out) {
    int tid = threadIdx.x;
    __shared__ float bs[256], bc[256];
    bs[tid] = psum[tid] + psum[tid + 256];
    bc[tid] = pcnt[tid] + pcnt[tid + 256];
    __syncthreads();
    for (int off = 128; off > 0; off >>= 1) {
        if (tid < off) { bs[tid] += bs[tid + off]; bc[tid] += bc[tid + off]; }
        __syncthreads();
    }
    if (tid == 0) out[0] = bs[0] / bc[0];
}

extern "C" void kernel_launch(void* const* d_in, const int* in_sizes, int n_in,
                              void* d_out, int out_size, void* d_ws, size_t ws_size,
                              hipStream_t stream) {
    (void)in_sizes; (void)n_in; (void)out_size; (void)ws_size;
    const float* text = (const float*)d_in[0];
    const float* img  = (const float*)d_in[1];
    const float* Wml  = (const float*)d_in[2];
    const float* Wmv  = (const float*)d_in[3];
    const float* tau  = (const float*)d_in[4];
    const int* pad    = (const int*)d_in[5];   // bool input lands as int32 per harness
    float* out = (float*)d_out;

    float* ws = (float*)d_ws;
    float* ip       = ws;                      // 131072
    float* Cm       = ws + 131072;             // 131072
    unsigned long long* mbits = (unsigned long long*)(ws + 262144); // 2048 u64 (4096 floats)
    float* denom    = ws + 266240;             // 131072
    float* siji     = ws + 397312;             // 131072
    float* crossM   = ws + 528384;             // 524288
    float* crossS   = ws + 1052672;            // 524288
    float* crossLog = ws + 1576960;            // 256
    float* psum     = ws + 1577216;            // 512
    float* pcnt     = ws + 1577728;            // 512  (total ~6.3 MB)

    hipLaunchKernelGGL(ip_kernel,   dim3(B_),  dim3(256), 0, stream, img, Wmv, ip);
    hipLaunchKernelGGL(c_kernel,    dim3(B_),  dim3(256), 0, stream, Wml, ip, tau, Cm);
    hipLaunchKernelGGL(mask_kernel, dim3(L_),  dim3(256), 0, stream, pad, mbits);
    hipLaunchKernelGGL(gemm_reduce_kernel, dim3(NT), dim3(256), 0, stream,
                       text, Cm, mbits, denom, siji, crossM, crossS);
    hipLaunchKernelGGL(cross_combine_kernel, dim3(B_), dim3(256), 0, stream,
                       crossM, crossS, crossLog);
    hipLaunchKernelGGL(loss_partial_kernel, dim3(ROWS / 256), dim3(256), 0, stream,
                       pad, denom, siji, crossLog, psum, pcnt);
    hipLaunchKernelGGL(final_kernel, dim3(1), dim3(256), 0, stream, psum, pcnt, out);
}